// Round 3
// baseline (450.019 us; speedup 1.0000x reference)
//
#include <hip/hip_runtime.h>
#include <hip/hip_bf16.h>
#include <math.h>
#include <stdint.h>

#define N_TOKENS 16384
#define DIM 4096
#define NEXP 64

typedef const __attribute__((address_space(1))) void gvoid_t;
typedef __attribute__((address_space(3))) void svoid_t;

constexpr int KC = 32;  // k-chunk per LDS stage

// ---------------- K1: logits = x @ W^T (fp32, K-split partials) ----------------
// lane = token (64 tokens/block); wave w owns experts [16w, 16w+16).
// x: global -> LDS via global_load_lds, source-XOR-swizzled (linear dest),
//    then ds_read_b128 with matching slot swizzle -> 32 x-floats in VGPRs.
// W: wave-uniform address -> s_load into SGPRs, FMA consumes SGPR operand.
__global__ __launch_bounds__(256, 6) void k1_gemm(const float* __restrict__ x,
                                                  const float* __restrict__ W,
                                                  float* __restrict__ P, int KS) {
  __shared__ float xlds[64 * KC];  // [row][32 floats], 16B-slot swizzled, 8 KB
  const int tid = threadIdx.x;
  const int lane = tid & 63;
  const int wid = __builtin_amdgcn_readfirstlane(tid >> 6);  // wave id 0..3
  const int tok0 = blockIdx.x * 64;
  const int k0 = blockIdx.y * KS;
  const int eg = wid * 16;  // expert base for this wave

  float2 acc2[16];
#pragma unroll
  for (int e = 0; e < 16; ++e) acc2[e] = make_float2(0.f, 0.f);

  const int ls = lane & 7;   // 16B slot within a row (glds staging)
  const int lr = lane >> 3;  // row offset within this glds instruction

  for (int kc = k0; kc < k0 + KS; kc += KC) {
    __syncthreads();  // all waves done reading previous tile
    // stage x[tok0..+63][kc..+31]: 2 glds per wave, 8 rows (1 KB) each.
    // LDS dest is linear; source is slot-XOR-permuted so that the
    // swizzled compute read below sees logical order. Each 8-lane group
    // reads exactly one aligned 128B line of x -> fully coalesced.
#pragma unroll
    for (int i = 0; i < 2; ++i) {
      const int r0 = wid * 16 + i * 8;  // wave-uniform row base
      const int r = r0 + lr;            // this lane's row
      const float* src =
          x + (size_t)(tok0 + r) * DIM + kc + 4 * (ls ^ (r & 7));
      float* dst = xlds + r0 * KC;  // uniform base; lane lands at +16B*lane
      __builtin_amdgcn_global_load_lds((gvoid_t*)src, (svoid_t*)dst, 16, 0, 0);
    }
    __syncthreads();  // vmcnt drained before reads

    // lane's token row -> 32 floats in VGPRs (swizzled ds_read_b128 x8)
    float4 xv[8];
#pragma unroll
    for (int c = 0; c < 8; ++c)
      xv[c] = *(const float4*)(xlds + lane * KC + 4 * (c ^ (lane & 7)));

    // 16 experts x 32 k: W via scalar loads (uniform addr), 512 FMAs
#pragma unroll
    for (int e = 0; e < 16; ++e) {
      const float* wr = W + (size_t)(eg + e) * DIM + kc;
#pragma unroll
      for (int c = 0; c < 8; ++c) {
        const float4 w4 = *(const float4*)(wr + c * 4);
        acc2[e].x = fmaf(xv[c].x, w4.x, acc2[e].x);
        acc2[e].y = fmaf(xv[c].y, w4.y, acc2[e].y);
        acc2[e].x = fmaf(xv[c].z, w4.z, acc2[e].x);
        acc2[e].y = fmaf(xv[c].w, w4.w, acc2[e].y);
      }
    }
  }

  // write P[split][token][eg..eg+15] (each lane: 64B contiguous of its row)
  float* prow =
      P + ((size_t)blockIdx.y * N_TOKENS + tok0 + lane) * NEXP + eg;
#pragma unroll
  for (int q = 0; q < 4; ++q) {
    float4 o;
    o.x = acc2[q * 4 + 0].x + acc2[q * 4 + 0].y;
    o.y = acc2[q * 4 + 1].x + acc2[q * 4 + 1].y;
    o.z = acc2[q * 4 + 2].x + acc2[q * 4 + 2].y;
    o.w = acc2[q * 4 + 3].x + acc2[q * 4 + 3].y;
    *(float4*)(prow + q * 4) = o;
  }
}

// ------------- K2: sum partials, softmax, top-2, chunk histograms -------------
__global__ __launch_bounds__(128) void k2_softmax_top2(const float* __restrict__ P,
                                                       int split,
                                                       float* __restrict__ topw,
                                                       int* __restrict__ sel,
                                                       int* __restrict__ cnt) {
  __shared__ int hist[NEXP];
  const int tid = threadIdx.x;
  const int t = blockIdx.x * 128 + tid;
  if (tid < NEXP) hist[tid] = 0;
  __syncthreads();

  float4 v[16];
  {
    const float* row = P + (size_t)t * NEXP;
#pragma unroll
    for (int c = 0; c < 16; ++c) v[c] = *(const float4*)(row + c * 4);
  }
  for (int s = 1; s < split; ++s) {
    const float* row = P + ((size_t)s * N_TOKENS + t) * NEXP;
#pragma unroll
    for (int c = 0; c < 16; ++c) {
      const float4 u = *(const float4*)(row + c * 4);
      v[c].x += u.x; v[c].y += u.y; v[c].z += u.z; v[c].w += u.w;
    }
  }

  float v0 = -INFINITY, v1 = -INFINITY;
  int i0 = 0, i1 = 0;
#define TOP2_STEP(val, idx)                                   \
  {                                                           \
    const float vv = (val);                                   \
    const int ee = (idx);                                     \
    if (vv > v0) { v1 = v0; i1 = i0; v0 = vv; i0 = ee; }      \
    else if (vv > v1) { v1 = vv; i1 = ee; }                   \
  }
#pragma unroll
  for (int c = 0; c < 16; ++c) {
    TOP2_STEP(v[c].x, c * 4 + 0);
    TOP2_STEP(v[c].y, c * 4 + 1);
    TOP2_STEP(v[c].z, c * 4 + 2);
    TOP2_STEP(v[c].w, c * 4 + 3);
  }
#undef TOP2_STEP

  float denom = 0.f;
#pragma unroll
  for (int c = 0; c < 16; ++c) {
    denom += expf(v[c].x - v0);
    denom += expf(v[c].y - v0);
    denom += expf(v[c].z - v0);
    denom += expf(v[c].w - v0);
  }
  const float w0 = 1.0f / denom;           // expf(0) == 1 exactly
  const float w1 = expf(v1 - v0) / denom;

  topw[t * 2 + 0] = w0;
  topw[t * 2 + 1] = w1;
  sel[t * 2 + 0] = i0;
  sel[t * 2 + 1] = i1;
  atomicAdd(&hist[i0], 1);
  atomicAdd(&hist[i1], 1);
  __syncthreads();
  if (tid < NEXP) cnt[blockIdx.x * NEXP + tid] = hist[tid];
}

// -------- K3: expert totals (counts out), exclusive offsets, chunk bases --------
__global__ void k3_scan(const int* __restrict__ cnt, int* __restrict__ cb,
                        float* __restrict__ counts_out) {
  __shared__ int tot[NEXP];
  const int e = threadIdx.x;  // 64 threads
  int run = 0;
  for (int p = 0; p < 128; ++p) run += cnt[p * NEXP + e];
  tot[e] = run;
  counts_out[e] = (float)run;
  __syncthreads();
  int g = 0;
  for (int q = 0; q < e; ++q) g += tot[q];
  int r = g;
  for (int p = 0; p < 128; ++p) {
    cb[p * NEXP + e] = r;
    r += cnt[p * NEXP + e];
  }
}

// ---------------- K4: stable scatter (counting-sort permutation) ----------------
__global__ __launch_bounds__(256) void k4_scatter(const int* __restrict__ sel,
                                                  const int* __restrict__ cb,
                                                  float* __restrict__ gout) {
  __shared__ int wcnt[4 * NEXP];
  const int tid = threadIdx.x;
  const int s = blockIdx.x * 256 + tid;
  const int e = sel[s];
  const int lane = tid & 63;
  const int wv = tid >> 6;
  wcnt[tid] = 0;
  __syncthreads();

  unsigned long long mask = ~0ull;
#pragma unroll
  for (int b = 0; b < 6; ++b) {
    const unsigned long long bb = __ballot((e >> b) & 1);
    mask &= ((e >> b) & 1) ? bb : ~bb;
  }
  const unsigned long long below = mask & ((1ull << lane) - 1ull);
  const int wr = __popcll(below);
  if (wr == 0) wcnt[wv * NEXP + e] = __popcll(mask);
  __syncthreads();

  int base = cb[blockIdx.x * NEXP + e];
  for (int w2 = 0; w2 < wv; ++w2) base += wcnt[w2 * NEXP + e];
  gout[base + wr] = (float)s;
}

extern "C" void kernel_launch(void* const* d_in, const int* in_sizes, int n_in,
                              void* d_out, int out_size, void* d_ws, size_t ws_size,
                              hipStream_t stream) {
  const float* x = (const float*)d_in[0];
  const float* W = (const float*)d_in[1];
  float* out = (float*)d_out;

  auto need = [](int s) {
    return (size_t)s * N_TOKENS * NEXP * 4 + (size_t)N_TOKENS * 2 * 4 +
           2 * (size_t)128 * NEXP * 4;
  };
  int split = 8;
  if (ws_size < need(8)) split = 4;
  if (ws_size < need(4)) split = (ws_size >= need(2)) ? 2 : 1;
  const int KS = DIM / split;

  float* P = (float*)d_ws;
  int* sel = (int*)((char*)d_ws + (size_t)split * N_TOKENS * NEXP * 4);
  int* cnt = sel + N_TOKENS * 2;
  int* cb = cnt + 128 * NEXP;

  hipLaunchKernelGGL(k1_gemm, dim3(N_TOKENS / 64, split), dim3(256), 0, stream,
                     x, W, P, KS);
  hipLaunchKernelGGL(k2_softmax_top2, dim3(N_TOKENS / 128), dim3(128), 0, stream,
                     P, split, out, sel, cnt);
  hipLaunchKernelGGL(k3_scan, dim3(1), dim3(64), 0, stream, cnt, cb,
                     out + 2 * N_TOKENS + 2 * N_TOKENS);
  hipLaunchKernelGGL(k4_scatter, dim3((2 * N_TOKENS) / 256), dim3(256), 0, stream,
                     sel, cb, out + 2 * N_TOKENS);
}

// Round 4
// 144.562 us; speedup vs baseline: 3.1130x; 3.1130x over previous
//
#include <hip/hip_runtime.h>
#include <hip/hip_bf16.h>
#include <math.h>
#include <stdint.h>

#define N_TOKENS 16384
#define DIM 4096
#define NEXP 64

typedef const __attribute__((address_space(1))) void gvoid_t;
typedef __attribute__((address_space(3))) void svoid_t;
typedef float f32x2 __attribute__((ext_vector_type(2)));

constexpr int MT = 128;  // tokens per block
constexpr int KC = 64;   // k-chunk staged per iteration
constexpr int TM = 4;    // tokens per thread
constexpr int TN = 8;    // experts per thread

#if __has_builtin(__builtin_elementwise_fma)
__device__ __forceinline__ f32x2 fma2(f32x2 a, f32x2 b, f32x2 c) {
  return __builtin_elementwise_fma(a, b, c);  // -> v_pk_fma_f32
}
#else
__device__ __forceinline__ f32x2 fma2(f32x2 a, f32x2 b, f32x2 c) {
  c.x = fmaf(a.x, b.x, c.x);
  c.y = fmaf(a.y, b.y, c.y);
  return c;
}
#endif

// ---------------- K1: logits = x @ W^T (fp32, K-split partials) ----------------
// Both operands staged via global_load_lds (coalesced). x LDS rows are
// 16B-slot XOR-swizzled (source-side permute, linear dest) so the
// 32-distinct-row compute read sits at the LDS banking floor. W reads are
// wave-broadcast (2 addrs/instr, conflict-free). Register tile 4 tok x 8 exp.
__global__ __launch_bounds__(256, 4) void k1_gemm(const float* __restrict__ x,
                                                  const float* __restrict__ W,
                                                  float* __restrict__ P, int KS) {
  __shared__ float xlds[MT * KC];    // [row][slot^key], 32 KB
  __shared__ float wlds[NEXP * KC];  // [exp][k], 16 KB
  const int tid = threadIdx.x;
  const int lane = tid & 63;
  const int wid = __builtin_amdgcn_readfirstlane(tid >> 6);  // wave 0..3
  const int tg = tid & 31;  // token slot: tokens tg + 32*i
  const int eg = tid >> 5;  // expert octet 0..7
  const int tok0 = blockIdx.x * MT;
  const int k0 = blockIdx.y * KS;

  const int lr = lane >> 4;     // row within one glds instr (4 rows x 256B)
  const int lslot = lane & 15;  // 16B slot within row
  const int keyt = tg & 15;     // compute-read swizzle key (same for all 4 toks)

  f32x2 acc[TM][TN] = {};

  for (int kc = k0; kc < k0 + KS; kc += KC) {
    __syncthreads();  // previous tile's readers done
    // stage x[tok0..+127][kc..+63]: 8 glds/wave, 4 rows (1 KB) each.
    // Source slot-XOR-permuted; LDS dest linear. Each glds reads 4
    // contiguous 256B row segments -> fully coalesced.
#pragma unroll
    for (int q = 0; q < 8; ++q) {
      const int r0 = 32 * wid + 4 * q;  // wave-uniform row base
      const int r = r0 + lr;
      const float* src =
          x + (size_t)(tok0 + r) * DIM + kc + 4 * (lslot ^ (r & 15));
      float* dst = xlds + r0 * KC;
      __builtin_amdgcn_global_load_lds((gvoid_t*)src, (svoid_t*)dst, 16, 0, 0);
    }
    // stage W[0..63][kc..+63]: 4 glds/wave, linear (broadcast reads need no
    // swizzle).
#pragma unroll
    for (int q = 0; q < 4; ++q) {
      const int e0 = 16 * wid + 4 * q;
      const int e = e0 + lr;
      const float* src = W + (size_t)e * DIM + kc + 4 * lslot;
      float* dst = wlds + e0 * KC;
      __builtin_amdgcn_global_load_lds((gvoid_t*)src, (svoid_t*)dst, 16, 0, 0);
    }
    __syncthreads();  // vmcnt drained at barrier

#pragma unroll
    for (int c = 0; c < KC / 4; ++c) {
      f32x2 xa[TM], xb[TM];
#pragma unroll
      for (int i = 0; i < TM; ++i) {
        const float4 t =
            *(const float4*)(xlds + (tg + 32 * i) * KC + 4 * (c ^ keyt));
        xa[i].x = t.x; xa[i].y = t.y;
        xb[i].x = t.z; xb[i].y = t.w;
      }
#pragma unroll
      for (int j = 0; j < TN; ++j) {
        const float4 w = *(const float4*)(wlds + (eg * TN + j) * KC + 4 * c);
        f32x2 wa, wb;
        wa.x = w.x; wa.y = w.y;
        wb.x = w.z; wb.y = w.w;
#pragma unroll
        for (int i = 0; i < TM; ++i) {
          acc[i][j] = fma2(xa[i], wa, acc[i][j]);
          acc[i][j] = fma2(xb[i], wb, acc[i][j]);
        }
      }
    }
  }

  // write partial logits: thread covers tokens tg+32i, experts eg*8..+8
#pragma unroll
  for (int i = 0; i < TM; ++i) {
    const int tok = tok0 + tg + 32 * i;
    float* prow = P + ((size_t)blockIdx.y * N_TOKENS + tok) * NEXP + eg * TN;
    float4 o0, o1;
    o0.x = acc[i][0].x + acc[i][0].y;
    o0.y = acc[i][1].x + acc[i][1].y;
    o0.z = acc[i][2].x + acc[i][2].y;
    o0.w = acc[i][3].x + acc[i][3].y;
    o1.x = acc[i][4].x + acc[i][4].y;
    o1.y = acc[i][5].x + acc[i][5].y;
    o1.z = acc[i][6].x + acc[i][6].y;
    o1.w = acc[i][7].x + acc[i][7].y;
    *(float4*)prow = o0;
    *(float4*)(prow + 4) = o1;
  }
}

// ------------- K2: sum partials, softmax, top-2, chunk histograms -------------
__global__ __launch_bounds__(128) void k2_softmax_top2(const float* __restrict__ P,
                                                       int split,
                                                       float* __restrict__ topw,
                                                       int* __restrict__ sel,
                                                       int* __restrict__ cnt) {
  __shared__ int hist[NEXP];
  const int tid = threadIdx.x;
  const int t = blockIdx.x * 128 + tid;
  if (tid < NEXP) hist[tid] = 0;
  __syncthreads();

  float4 v[16];
  {
    const float* row = P + (size_t)t * NEXP;
#pragma unroll
    for (int c = 0; c < 16; ++c) v[c] = *(const float4*)(row + c * 4);
  }
  for (int s = 1; s < split; ++s) {
    const float* row = P + ((size_t)s * N_TOKENS + t) * NEXP;
#pragma unroll
    for (int c = 0; c < 16; ++c) {
      const float4 u = *(const float4*)(row + c * 4);
      v[c].x += u.x; v[c].y += u.y; v[c].z += u.z; v[c].w += u.w;
    }
  }

  float v0 = -INFINITY, v1 = -INFINITY;
  int i0 = 0, i1 = 0;
#define TOP2_STEP(val, idx)                                   \
  {                                                           \
    const float vv = (val);                                   \
    const int ee = (idx);                                     \
    if (vv > v0) { v1 = v0; i1 = i0; v0 = vv; i0 = ee; }      \
    else if (vv > v1) { v1 = vv; i1 = ee; }                   \
  }
#pragma unroll
  for (int c = 0; c < 16; ++c) {
    TOP2_STEP(v[c].x, c * 4 + 0);
    TOP2_STEP(v[c].y, c * 4 + 1);
    TOP2_STEP(v[c].z, c * 4 + 2);
    TOP2_STEP(v[c].w, c * 4 + 3);
  }
#undef TOP2_STEP

  float denom = 0.f;
#pragma unroll
  for (int c = 0; c < 16; ++c) {
    denom += expf(v[c].x - v0);
    denom += expf(v[c].y - v0);
    denom += expf(v[c].z - v0);
    denom += expf(v[c].w - v0);
  }
  const float w0 = 1.0f / denom;           // expf(0) == 1 exactly
  const float w1 = expf(v1 - v0) / denom;

  topw[t * 2 + 0] = w0;
  topw[t * 2 + 1] = w1;
  sel[t * 2 + 0] = i0;
  sel[t * 2 + 1] = i1;
  atomicAdd(&hist[i0], 1);
  atomicAdd(&hist[i1], 1);
  __syncthreads();
  if (tid < NEXP) cnt[blockIdx.x * NEXP + tid] = hist[tid];
}

// -------- K3: expert totals (counts out), exclusive offsets, chunk bases --------
__global__ void k3_scan(const int* __restrict__ cnt, int* __restrict__ cb,
                        float* __restrict__ counts_out) {
  __shared__ int tot[NEXP];
  const int e = threadIdx.x;  // 64 threads
  int run = 0;
  for (int p = 0; p < 128; ++p) run += cnt[p * NEXP + e];
  tot[e] = run;
  counts_out[e] = (float)run;
  __syncthreads();
  int g = 0;
  for (int q = 0; q < e; ++q) g += tot[q];
  int r = g;
  for (int p = 0; p < 128; ++p) {
    cb[p * NEXP + e] = r;
    r += cnt[p * NEXP + e];
  }
}

// ---------------- K4: stable scatter (counting-sort permutation) ----------------
__global__ __launch_bounds__(256) void k4_scatter(const int* __restrict__ sel,
                                                  const int* __restrict__ cb,
                                                  float* __restrict__ gout) {
  __shared__ int wcnt[4 * NEXP];
  const int tid = threadIdx.x;
  const int s = blockIdx.x * 256 + tid;
  const int e = sel[s];
  const int lane = tid & 63;
  const int wv = tid >> 6;
  wcnt[tid] = 0;
  __syncthreads();

  unsigned long long mask = ~0ull;
#pragma unroll
  for (int b = 0; b < 6; ++b) {
    const unsigned long long bb = __ballot((e >> b) & 1);
    mask &= ((e >> b) & 1) ? bb : ~bb;
  }
  const unsigned long long below = mask & ((1ull << lane) - 1ull);
  const int wr = __popcll(below);
  if (wr == 0) wcnt[wv * NEXP + e] = __popcll(mask);
  __syncthreads();

  int base = cb[blockIdx.x * NEXP + e];
  for (int w2 = 0; w2 < wv; ++w2) base += wcnt[w2 * NEXP + e];
  gout[base + wr] = (float)s;
}

extern "C" void kernel_launch(void* const* d_in, const int* in_sizes, int n_in,
                              void* d_out, int out_size, void* d_ws, size_t ws_size,
                              hipStream_t stream) {
  const float* x = (const float*)d_in[0];
  const float* W = (const float*)d_in[1];
  float* out = (float*)d_out;

  auto need = [](int s) {
    return (size_t)s * N_TOKENS * NEXP * 4 + (size_t)N_TOKENS * 2 * 4 +
           2 * (size_t)128 * NEXP * 4;
  };
  int split = 8;
  if (ws_size < need(8)) split = 4;
  if (ws_size < need(4)) split = (ws_size >= need(2)) ? 2 : 1;
  const int KS = DIM / split;

  float* P = (float*)d_ws;
  int* sel = (int*)((char*)d_ws + (size_t)split * N_TOKENS * NEXP * 4);
  int* cnt = sel + N_TOKENS * 2;
  int* cb = cnt + 128 * NEXP;

  hipLaunchKernelGGL(k1_gemm, dim3(N_TOKENS / MT, split), dim3(256), 0, stream,
                     x, W, P, KS);
  hipLaunchKernelGGL(k2_softmax_top2, dim3(N_TOKENS / 128), dim3(128), 0, stream,
                     P, split, out, sel, cnt);
  hipLaunchKernelGGL(k3_scan, dim3(1), dim3(64), 0, stream, cnt, cb,
                     out + 2 * N_TOKENS + 2 * N_TOKENS);
  hipLaunchKernelGGL(k4_scatter, dim3((2 * N_TOKENS) / 256), dim3(256), 0, stream,
                     sel, cb, out + 2 * N_TOKENS);
}